// Round 1
// baseline (628.971 us; speedup 1.0000x reference)
//
#include <hip/hip_runtime.h>
#include <math.h>

#define N_CLASSES 100
#define EPSILON 1e-7f

// d_ws layout: int cnt[3*N_CLASSES]
//   cnt[0..99]    = row_sum  (histogram of y_true)
//   cnt[100..199] = col_sum  (histogram of argmax(y_pred))
//   cnt[200..299] = diag     (count of t == p)

__global__ void zero_counters(int* __restrict__ cnt) {
    int i = threadIdx.x;
    if (i < 3 * N_CLASSES) cnt[i] = 0;
}

__global__ __launch_bounds__(256)
void argmax_hist(const float* __restrict__ y_pred,
                 const int* __restrict__ y_true,
                 int* __restrict__ cnt, int n_rows) {
    __shared__ int h_true[N_CLASSES];
    __shared__ int h_pred[N_CLASSES];
    __shared__ int h_diag[N_CLASSES];
    for (int i = threadIdx.x; i < N_CLASSES; i += blockDim.x) {
        h_true[i] = 0; h_pred[i] = 0; h_diag[i] = 0;
    }
    __syncthreads();

    int row    = blockIdx.x * blockDim.x + threadIdx.x;
    int stride = gridDim.x * blockDim.x;
    for (; row < n_rows; row += stride) {
        // 100 floats = 25 float4; row base is 16B-aligned (400 % 16 == 0)
        const float4* p = reinterpret_cast<const float4*>(
            y_pred + (size_t)row * N_CLASSES);
        float best = -INFINITY;
        int   bi   = 0;
        #pragma unroll
        for (int j = 0; j < 25; ++j) {
            float4 v = p[j];
            int base = j * 4;
            // strict '>' keeps the FIRST max, matching jnp.argmax
            if (v.x > best) { best = v.x; bi = base;     }
            if (v.y > best) { best = v.y; bi = base + 1; }
            if (v.z > best) { best = v.z; bi = base + 2; }
            if (v.w > best) { best = v.w; bi = base + 3; }
        }
        int t = y_true[row];
        atomicAdd(&h_true[t], 1);
        atomicAdd(&h_pred[bi], 1);
        if (t == bi) atomicAdd(&h_diag[t], 1);
    }

    __syncthreads();
    for (int i = threadIdx.x; i < N_CLASSES; i += blockDim.x) {
        int a = h_true[i], b = h_pred[i], c = h_diag[i];
        if (a) atomicAdd(&cnt[i], a);
        if (b) atomicAdd(&cnt[N_CLASSES + i], b);
        if (c) atomicAdd(&cnt[2 * N_CLASSES + i], c);
    }
}

__global__ void finalize(const int* __restrict__ cnt,
                         float* __restrict__ out, int n_rows) {
    __shared__ float partial[128];
    int i = threadIdx.x;
    float v = 0.0f;
    if (i < N_CLASSES) {
        float row_sum = (float)cnt[i];
        float col_sum = (float)cnt[N_CLASSES + i];
        float diag    = (float)cnt[2 * N_CLASSES + i];
        float total   = (float)n_rows;
        float TN = total - row_sum - col_sum + diag;
        float FP = row_sum - diag;
        v = TN / (TN + FP + EPSILON);
    }
    partial[i] = v;
    __syncthreads();
    for (int s = 64; s > 0; s >>= 1) {
        if (i < s) partial[i] += partial[i + s];
        __syncthreads();
    }
    if (i == 0) out[0] = partial[0] / (float)N_CLASSES;
}

extern "C" void kernel_launch(void* const* d_in, const int* in_sizes, int n_in,
                              void* d_out, int out_size, void* d_ws, size_t ws_size,
                              hipStream_t stream) {
    const float* y_pred = (const float*)d_in[0];
    const int*   y_true = (const int*)d_in[1];
    int n_rows = in_sizes[1];   // 1,000,000

    int*   cnt = (int*)d_ws;
    float* out = (float*)d_out;

    zero_counters<<<1, 384, 0, stream>>>(cnt);

    int blocks = (n_rows + 255) / 256;
    argmax_hist<<<blocks, 256, 0, stream>>>(y_pred, y_true, cnt, n_rows);

    finalize<<<1, 128, 0, stream>>>(cnt, out, n_rows);
}

// Round 2
// 557.427 us; speedup vs baseline: 1.1283x; 1.1283x over previous
//
#include <hip/hip_runtime.h>
#include <math.h>

#define N_CLASSES 100
#define EPSILON 1e-7f

// d_ws layout: int cnt[3*N_CLASSES]
//   cnt[0..99]    = row_sum  (histogram of y_true)
//   cnt[100..199] = col_sum  (histogram of argmax(y_pred))
//   cnt[200..299] = diag     (count of t == p)

__global__ void zero_counters(int* __restrict__ cnt) {
    int i = threadIdx.x;
    if (i < 3 * N_CLASSES) cnt[i] = 0;
}

// 16 lanes cooperate on one row. Lane sub loads float4 at element 4*sub
// (elements 0..63) and, for sub<9, at element 64+4*sub (elements 64..99).
// Every wave instruction touches 4 contiguous 256B segments -> coalesced.
__global__ __launch_bounds__(256)
void argmax_hist(const float* __restrict__ y_pred,
                 const int* __restrict__ y_true,
                 int* __restrict__ cnt, int n_rows) {
    __shared__ int h_true[N_CLASSES];
    __shared__ int h_pred[N_CLASSES];
    __shared__ int h_diag[N_CLASSES];
    for (int i = threadIdx.x; i < N_CLASSES; i += blockDim.x) {
        h_true[i] = 0; h_pred[i] = 0; h_diag[i] = 0;
    }
    __syncthreads();

    const int sub = threadIdx.x & 15;                       // lane within quarter-wave
    const int q   = (blockIdx.x * blockDim.x + threadIdx.x) >> 4;  // global quarter id
    const int Q   = (gridDim.x * blockDim.x) >> 4;

    for (int row = q; row < n_rows; row += Q) {
        const float4* rp4 = reinterpret_cast<const float4*>(
            y_pred + (size_t)row * N_CLASSES);

        float4 v0 = rp4[sub];                 // elements 4*sub .. 4*sub+3
        float best = v0.x; int bi = 4 * sub;
        if (v0.y > best) { best = v0.y; bi = 4 * sub + 1; }
        if (v0.z > best) { best = v0.z; bi = 4 * sub + 2; }
        if (v0.w > best) { best = v0.w; bi = 4 * sub + 3; }

        if (sub < 9) {                        // elements 64+4*sub .. (64..99)
            float4 v1 = rp4[16 + sub];
            int b2 = 64 + 4 * sub;
            if (v1.x > best) { best = v1.x; bi = b2;     }
            if (v1.y > best) { best = v1.y; bi = b2 + 1; }
            if (v1.z > best) { best = v1.z; bi = b2 + 2; }
            if (v1.w > best) { best = v1.w; bi = b2 + 3; }
        }

        // pack (value, first-index) into one 64-bit max-reduction key:
        // monotone float bits in high 32, ~idx in low 32 (ties -> smaller idx)
        unsigned u = __float_as_uint(best);
        unsigned mono = u ^ (unsigned)(((int)u >> 31) | 0x80000000);
        unsigned long long key =
            ((unsigned long long)mono << 32) | (unsigned)(~bi);

        #pragma unroll
        for (int m = 1; m <= 8; m <<= 1) {
            unsigned long long other = __shfl_xor(key, m, 16);
            if (other > key) key = other;
        }

        if (sub == 0) {
            int rbi = (int)(~(unsigned)(key & 0xffffffffull));
            int t = y_true[row];
            atomicAdd(&h_true[t], 1);
            atomicAdd(&h_pred[rbi], 1);
            if (t == rbi) atomicAdd(&h_diag[t], 1);
        }
    }

    __syncthreads();
    for (int i = threadIdx.x; i < N_CLASSES; i += blockDim.x) {
        int a = h_true[i], b = h_pred[i], c = h_diag[i];
        if (a) atomicAdd(&cnt[i], a);
        if (b) atomicAdd(&cnt[N_CLASSES + i], b);
        if (c) atomicAdd(&cnt[2 * N_CLASSES + i], c);
    }
}

__global__ void finalize(const int* __restrict__ cnt,
                         float* __restrict__ out, int n_rows) {
    __shared__ float partial[128];
    int i = threadIdx.x;
    float v = 0.0f;
    if (i < N_CLASSES) {
        float row_sum = (float)cnt[i];
        float col_sum = (float)cnt[N_CLASSES + i];
        float diag    = (float)cnt[2 * N_CLASSES + i];
        float total   = (float)n_rows;
        float TN = total - row_sum - col_sum + diag;
        float FP = row_sum - diag;
        v = TN / (TN + FP + EPSILON);
    }
    partial[i] = v;
    __syncthreads();
    for (int s = 64; s > 0; s >>= 1) {
        if (i < s) partial[i] += partial[i + s];
        __syncthreads();
    }
    if (i == 0) out[0] = partial[0] / (float)N_CLASSES;
}

extern "C" void kernel_launch(void* const* d_in, const int* in_sizes, int n_in,
                              void* d_out, int out_size, void* d_ws, size_t ws_size,
                              hipStream_t stream) {
    const float* y_pred = (const float*)d_in[0];
    const int*   y_true = (const int*)d_in[1];
    int n_rows = in_sizes[1];   // 1,000,000

    int*   cnt = (int*)d_ws;
    float* out = (float*)d_out;

    zero_counters<<<1, 384, 0, stream>>>(cnt);

    // 2048 blocks x 256 threads = 32 waves/CU resident (exactly fills),
    // 16 rows per block per grid-stride iteration.
    argmax_hist<<<2048, 256, 0, stream>>>(y_pred, y_true, cnt, n_rows);

    finalize<<<1, 128, 0, stream>>>(cnt, out, n_rows);
}

// Round 3
// 533.490 us; speedup vs baseline: 1.1790x; 1.0449x over previous
//
#include <hip/hip_runtime.h>
#include <math.h>

#define N_CLASSES 100
#define EPSILON 1e-7f

// d_ws layout: int cnt[3*N_CLASSES]
//   cnt[0..99]    = row_sum  (histogram of y_true)
//   cnt[100..199] = col_sum  (histogram of argmax(y_pred))
//   cnt[200..299] = diag     (count of t == p)

__global__ void zero_counters(int* __restrict__ cnt) {
    int i = threadIdx.x;
    if (i < 3 * N_CLASSES) cnt[i] = 0;
}

__device__ __forceinline__ unsigned long long
row_key(const float4& va, const float4& vb, bool hi, int sub) {
    // per-lane argmax over this lane's chunk; strict '>' keeps FIRST max
    float best = va.x; int bi = 4 * sub;
    if (va.y > best) { best = va.y; bi = 4 * sub + 1; }
    if (va.z > best) { best = va.z; bi = 4 * sub + 2; }
    if (va.w > best) { best = va.w; bi = 4 * sub + 3; }
    if (hi) {
        int b2 = 64 + 4 * sub;
        if (vb.x > best) { best = vb.x; bi = b2;     }
        if (vb.y > best) { best = vb.y; bi = b2 + 1; }
        if (vb.z > best) { best = vb.z; bi = b2 + 2; }
        if (vb.w > best) { best = vb.w; bi = b2 + 3; }
    }
    // monotone float bits high, ~idx low (equal values -> smaller idx wins)
    unsigned u = __float_as_uint(best);
    unsigned mono = u ^ (unsigned)(((int)u >> 31) | 0x80000000);
    return ((unsigned long long)mono << 32) | (unsigned)(~bi);
}

// 16 lanes per row, 4 rows per quarter-wave per iteration.
// One wave covers 16 consecutive rows = 6400 contiguous bytes.
__global__ __launch_bounds__(256)
void argmax_hist(const float* __restrict__ y_pred,
                 const int* __restrict__ y_true,
                 int* __restrict__ cnt, int n_rows) {
    __shared__ int h_true[N_CLASSES];
    __shared__ int h_pred[N_CLASSES];
    __shared__ int h_diag[N_CLASSES];
    for (int i = threadIdx.x; i < N_CLASSES; i += blockDim.x) {
        h_true[i] = 0; h_pred[i] = 0; h_diag[i] = 0;
    }
    __syncthreads();

    const int sub = threadIdx.x & 15;
    const int q   = (blockIdx.x * blockDim.x + threadIdx.x) >> 4;
    const int Q   = (gridDim.x * blockDim.x) >> 4;
    const bool hi = sub < 9;
    const int n_groups = n_rows >> 2;   // groups of 4 rows

    for (int g = q; g < n_groups; g += Q) {
        const size_t r0 = (size_t)g * 4;
        const float4* p = reinterpret_cast<const float4*>(
            y_pred + r0 * N_CLASSES);     // row i starts at float4 index 25*i

        // issue all 8 loads up front for max MLP
        float4 a0 = p[sub];
        float4 a1 = p[25 + sub];
        float4 a2 = p[50 + sub];
        float4 a3 = p[75 + sub];
        float4 b0, b1, b2, b3;
        if (hi) {
            b0 = p[16 + sub];
            b1 = p[41 + sub];
            b2 = p[66 + sub];
            b3 = p[91 + sub];
        }

        unsigned long long k0 = row_key(a0, b0, hi, sub);
        unsigned long long k1 = row_key(a1, b1, hi, sub);
        unsigned long long k2 = row_key(a2, b2, hi, sub);
        unsigned long long k3 = row_key(a3, b3, hi, sub);

        #pragma unroll
        for (int m = 1; m <= 8; m <<= 1) {
            unsigned long long o0 = __shfl_xor(k0, m, 16);
            unsigned long long o1 = __shfl_xor(k1, m, 16);
            unsigned long long o2 = __shfl_xor(k2, m, 16);
            unsigned long long o3 = __shfl_xor(k3, m, 16);
            if (o0 > k0) k0 = o0;
            if (o1 > k1) k1 = o1;
            if (o2 > k2) k2 = o2;
            if (o3 > k3) k3 = o3;
        }

        if (sub == 0) {
            int4 t4 = *reinterpret_cast<const int4*>(y_true + r0);
            int p0 = (int)~(unsigned)k0;
            int p1 = (int)~(unsigned)k1;
            int p2 = (int)~(unsigned)k2;
            int p3 = (int)~(unsigned)k3;
            atomicAdd(&h_pred[p0], 1);
            atomicAdd(&h_pred[p1], 1);
            atomicAdd(&h_pred[p2], 1);
            atomicAdd(&h_pred[p3], 1);
            atomicAdd(&h_true[t4.x], 1);
            atomicAdd(&h_true[t4.y], 1);
            atomicAdd(&h_true[t4.z], 1);
            atomicAdd(&h_true[t4.w], 1);
            if (t4.x == p0) atomicAdd(&h_diag[t4.x], 1);
            if (t4.y == p1) atomicAdd(&h_diag[t4.y], 1);
            if (t4.z == p2) atomicAdd(&h_diag[t4.z], 1);
            if (t4.w == p3) atomicAdd(&h_diag[t4.w], 1);
        }
    }

    // tail rows (none for n_rows % 4 == 0, kept for safety)
    int tail_start = n_groups << 2;
    int tail = n_rows - tail_start;
    if (q < tail) {
        int row = tail_start + q;
        const float4* p = reinterpret_cast<const float4*>(
            y_pred + (size_t)row * N_CLASSES);
        float4 a = p[sub];
        float4 b;
        if (hi) b = p[16 + sub];
        unsigned long long k = row_key(a, b, hi, sub);
        #pragma unroll
        for (int m = 1; m <= 8; m <<= 1) {
            unsigned long long o = __shfl_xor(k, m, 16);
            if (o > k) k = o;
        }
        if (sub == 0) {
            int pi = (int)~(unsigned)k;
            int t = y_true[row];
            atomicAdd(&h_pred[pi], 1);
            atomicAdd(&h_true[t], 1);
            if (t == pi) atomicAdd(&h_diag[t], 1);
        }
    }

    __syncthreads();
    for (int i = threadIdx.x; i < N_CLASSES; i += blockDim.x) {
        int a = h_true[i], b = h_pred[i], c = h_diag[i];
        if (a) atomicAdd(&cnt[i], a);
        if (b) atomicAdd(&cnt[N_CLASSES + i], b);
        if (c) atomicAdd(&cnt[2 * N_CLASSES + i], c);
    }
}

__global__ void finalize(const int* __restrict__ cnt,
                         float* __restrict__ out, int n_rows) {
    __shared__ float partial[128];
    int i = threadIdx.x;
    float v = 0.0f;
    if (i < N_CLASSES) {
        float row_sum = (float)cnt[i];
        float col_sum = (float)cnt[N_CLASSES + i];
        float diag    = (float)cnt[2 * N_CLASSES + i];
        float total   = (float)n_rows;
        float TN = total - row_sum - col_sum + diag;
        float FP = row_sum - diag;
        v = TN / (TN + FP + EPSILON);
    }
    partial[i] = v;
    __syncthreads();
    for (int s = 64; s > 0; s >>= 1) {
        if (i < s) partial[i] += partial[i + s];
        __syncthreads();
    }
    if (i == 0) out[0] = partial[0] / (float)N_CLASSES;
}

extern "C" void kernel_launch(void* const* d_in, const int* in_sizes, int n_in,
                              void* d_out, int out_size, void* d_ws, size_t ws_size,
                              hipStream_t stream) {
    const float* y_pred = (const float*)d_in[0];
    const int*   y_true = (const int*)d_in[1];
    int n_rows = in_sizes[1];   // 1,000,000

    int*   cnt = (int*)d_ws;
    float* out = (float*)d_out;

    zero_counters<<<1, 384, 0, stream>>>(cnt);

    // 2048 blocks x 256 threads = 32 waves/CU resident; 64 rows per block
    // per grid-stride iteration (16 quarter-waves x 4 rows).
    argmax_hist<<<2048, 256, 0, stream>>>(y_pred, y_true, cnt, n_rows);

    finalize<<<1, 128, 0, stream>>>(cnt, out, n_rows);
}